// Round 1
// baseline (247.352 us; speedup 1.0000x reference)
//
#include <hip/hip_runtime.h>
#include <hip/hip_bf16.h>
#include <float.h>

// Problem constants (from setup_inputs): B=4096, D=512, N=2B=8192, temp=0.5
#define BN_ 4096
#define DD  512
#define NN  8192
#define SCALE 2.0f   // 1/temperature

typedef unsigned short u16;
typedef __attribute__((ext_vector_type(8))) short short8;   // 8 bf16 = 4 VGPRs
typedef __attribute__((ext_vector_type(4))) float floatx4;  // MFMA acc

struct alignas(8) U16x4 { u16 x, y, z, w; };

__device__ __forceinline__ u16 f2bf(float f) {
    union { float f; unsigned u; } c; c.f = f;
    unsigned u = c.u;
    unsigned r = (u + 0x7fffu + ((u >> 16) & 1u)) >> 16;   // RNE
    return (u16)r;
}

__device__ __forceinline__ void async_copy16(const u16* g, u16* l) {
    __builtin_amdgcn_global_load_lds(
        (const __attribute__((address_space(1))) void*)g,
        (__attribute__((address_space(3))) void*)l, 16, 0, 0);
}

// ---------------- kernel 1: fp32 -> bf16 concat ----------------
__global__ __launch_bounds__(256) void convert_kernel(const float* __restrict__ hi,
                                                      const float* __restrict__ hj,
                                                      u16* __restrict__ H) {
    int t = blockIdx.x * 256 + threadIdx.x;       // 1,048,576 threads
    int e = t * 4;
    const int BD = BN_ * DD;
    const float* src = (e < BD) ? (hi + e) : (hj + (e - BD));
    float4 v = *(const float4*)src;
    U16x4 o;
    o.x = f2bf(v.x); o.y = f2bf(v.y); o.z = f2bf(v.z); o.w = f2bf(v.w);
    *(U16x4*)(H + e) = o;
}

// ---------------- kernel 2: Gram tile + online softmax partials ----------------
// grid (64 colTiles, 64 rowTiles), block 256 (4 waves, 2x2 of 64x64 quadrants)
__global__ __launch_bounds__(256, 2) void gram_kernel(const u16* __restrict__ H,
                                                      float* __restrict__ Mpart,
                                                      float* __restrict__ Spart) {
    __shared__ u16 As[128 * 64];
    __shared__ u16 Bs[128 * 64];
    __shared__ float Mw[2][128];
    __shared__ float Sw[2][128];

    const int tid  = threadIdx.x;
    const int lane = tid & 63;
    const int wid  = tid >> 6;
    const int quad = lane >> 4;
    const int ln15 = lane & 15;
    const int waveRow = (wid >> 1) * 64;
    const int waveCol = (wid & 1) * 64;
    const int rowBase = blockIdx.y * 128;
    const int colBase = blockIdx.x * 128;

    floatx4 acc[4][4];
#pragma unroll
    for (int i = 0; i < 4; i++)
#pragma unroll
        for (int j = 0; j < 4; j++) acc[i][j] = (floatx4)0.0f;

    for (int k0 = 0; k0 < DD; k0 += 64) {
        // stage 128x64 A tile and B tile, 16B per thread per iter
#pragma unroll
        for (int i = 0; i < 4; i++) {
            int slot = i * 256 + tid;           // 0..1023
            int row  = slot >> 3;               // 0..127
            int kc   = slot & 7;                // 16B chunk within row
            const u16* ga = H + (size_t)(rowBase + row) * DD + k0 + kc * 8;
            const u16* gb = H + (size_t)(colBase + row) * DD + k0 + kc * 8;
            async_copy16(ga, &As[slot * 8]);
            async_copy16(gb, &Bs[slot * 8]);
        }
        __syncthreads();   // drains vmcnt before LDS reads

#pragma unroll
        for (int kk = 0; kk < 64; kk += 32) {
            short8 a[4], b[4];
#pragma unroll
            for (int tm = 0; tm < 4; tm++)
                a[tm] = *(const short8*)&As[(waveRow + tm * 16 + ln15) * 64 + kk + quad * 8];
#pragma unroll
            for (int tn = 0; tn < 4; tn++)
                b[tn] = *(const short8*)&Bs[(waveCol + tn * 16 + ln15) * 64 + kk + quad * 8];
#pragma unroll
            for (int tm = 0; tm < 4; tm++)
#pragma unroll
                for (int tn = 0; tn < 4; tn++)
                    acc[tm][tn] = __builtin_amdgcn_mfma_f32_16x16x32_bf16(
                        a[tm], b[tn], acc[tm][tn], 0, 0, 0);
        }
        __syncthreads();
    }

    // Epilogue: per-row (max, sumexp) over this wave's 64 cols.
    // C/D layout: col = ln15, row = quad*4 + reg  (per 16x16 subtile)
    float ml[4][4], sl[4][4];
#pragma unroll
    for (int tm = 0; tm < 4; tm++) {
#pragma unroll
        for (int r = 0; r < 4; r++) {
            int grow = rowBase + waveRow + tm * 16 + quad * 4 + r;
            float vals[4];
            float vmax = -FLT_MAX;
#pragma unroll
            for (int tn = 0; tn < 4; tn++) {
                float v = SCALE * acc[tm][tn][r];
                int gcol = colBase + waveCol + tn * 16 + ln15;
                if (gcol == grow) v = -FLT_MAX;   // exclude diagonal
                vals[tn] = v;
                vmax = fmaxf(vmax, v);
            }
            float s = 0.0f;
#pragma unroll
            for (int tn = 0; tn < 4; tn++) s += __expf(vals[tn] - vmax);
            // butterfly across the 16 lanes sharing this row group
#pragma unroll
            for (int msk = 1; msk < 16; msk <<= 1) {
                float pm = __shfl_xor(vmax, msk);
                float ps = __shfl_xor(s, msk);
                float mn = fmaxf(vmax, pm);
                s = s * __expf(vmax - mn) + ps * __expf(pm - mn);
                vmax = mn;
            }
            ml[tm][r] = vmax; sl[tm][r] = s;
        }
    }

    if (ln15 == 0) {
#pragma unroll
        for (int tm = 0; tm < 4; tm++)
#pragma unroll
            for (int r = 0; r < 4; r++) {
                int rl = waveRow + tm * 16 + quad * 4 + r;
                Mw[wid & 1][rl] = ml[tm][r];
                Sw[wid & 1][rl] = sl[tm][r];
            }
    }
    __syncthreads();

    if (tid < 128) {
        float m0 = Mw[0][tid], s0 = Sw[0][tid];
        float m1 = Mw[1][tid], s1 = Sw[1][tid];
        float mn = fmaxf(m0, m1);
        float s  = s0 * __expf(m0 - mn) + s1 * __expf(m1 - mn);
        size_t idx = (size_t)blockIdx.x * NN + rowBase + tid;
        Mpart[idx] = mn;
        Spart[idx] = s;
    }
}

// ---------------- kernel 3: positive pairs (exact fp32) ----------------
// one wave per row r<4096: dot(h_i[r], h_j[r]); sum_N pos = 4 * sum_r dot
__global__ __launch_bounds__(256) void pos_kernel(const float* __restrict__ hi,
                                                  const float* __restrict__ hj,
                                                  float* __restrict__ out) {
    int lane = threadIdx.x & 63;
    int wid  = threadIdx.x >> 6;
    int r = blockIdx.x * 4 + wid;   // 0..4095
    const float* a = hi + (size_t)r * DD + lane * 8;
    const float* b = hj + (size_t)r * DD + lane * 8;
    float4 a0 = *(const float4*)a;
    float4 a1 = *(const float4*)(a + 4);
    float4 b0 = *(const float4*)b;
    float4 b1 = *(const float4*)(b + 4);
    float dot = a0.x * b0.x + a0.y * b0.y + a0.z * b0.z + a0.w * b0.w +
                a1.x * b1.x + a1.y * b1.y + a1.z * b1.z + a1.w * b1.w;
#pragma unroll
    for (int msk = 1; msk < 64; msk <<= 1) dot += __shfl_xor(dot, msk);
    if (lane == 0) atomicAdd(out, dot * (-4.0f / (float)NN));
}

// ---------------- kernel 4: combine partials -> sum(lse)/N ----------------
__global__ __launch_bounds__(256) void lse_kernel(const float* __restrict__ Mpart,
                                                  const float* __restrict__ Spart,
                                                  float* __restrict__ out) {
    __shared__ float red[256];
    int tid = threadIdx.x;
    int r = blockIdx.x * 256 + tid;   // 0..8191
    float m = Mpart[r], s = Spart[r];
    for (int c = 1; c < 64; c++) {
        float mc = Mpart[(size_t)c * NN + r];
        float sc = Spart[(size_t)c * NN + r];
        float mn = fmaxf(m, mc);
        s = s * __expf(m - mn) + sc * __expf(mc - mn);
        m = mn;
    }
    float lse = m + logf(s);
    red[tid] = lse;
    __syncthreads();
    for (int st = 128; st > 0; st >>= 1) {
        if (tid < st) red[tid] += red[tid + st];
        __syncthreads();
    }
    if (tid == 0) atomicAdd(out, red[0] * (1.0f / (float)NN));
}

extern "C" void kernel_launch(void* const* d_in, const int* in_sizes, int n_in,
                              void* d_out, int out_size, void* d_ws, size_t ws_size,
                              hipStream_t stream) {
    const float* hi = (const float*)d_in[0];
    const float* hj = (const float*)d_in[1];
    float* out = (float*)d_out;

    // workspace layout
    u16*   H     = (u16*)d_ws;                                   // 8 MB
    float* Mpart = (float*)((char*)d_ws + (size_t)8 * 1024 * 1024);      // 2 MB
    float* Spart = (float*)((char*)d_ws + (size_t)10 * 1024 * 1024);     // 2 MB

    hipMemsetAsync(d_out, 0, sizeof(float), stream);

    convert_kernel<<<4096, 256, 0, stream>>>(hi, hj, H);

    dim3 gg(64, 64);
    gram_kernel<<<gg, 256, 0, stream>>>(H, Mpart, Spart);

    pos_kernel<<<1024, 256, 0, stream>>>(hi, hj, out);

    lse_kernel<<<32, 256, 0, stream>>>(Mpart, Spart, out);
}

// Round 2
// 160.037 us; speedup vs baseline: 1.5456x; 1.5456x over previous
//
#include <hip/hip_runtime.h>
#include <hip/hip_bf16.h>
#include <float.h>

// B=4096, D=512, N=8192, temp=0.5
#define BN_ 4096
#define DD  512
#define NN  8192
#define SCALE 2.0f   // 1/temperature

typedef unsigned short u16;
typedef __attribute__((ext_vector_type(8))) short short8;   // 8 bf16 = 4 VGPRs
typedef __attribute__((ext_vector_type(4))) float floatx4;  // MFMA acc

struct alignas(8) U16x4 { u16 x, y, z, w; };

__device__ __forceinline__ u16 f2bf(float f) {
    union { float f; unsigned u; } c; c.f = f;
    unsigned u = c.u;
    unsigned r = (u + 0x7fffu + ((u >> 16) & 1u)) >> 16;   // RNE
    return (u16)r;
}

__device__ __forceinline__ void async_copy16(const u16* g, u16* l) {
    __builtin_amdgcn_global_load_lds(
        (const __attribute__((address_space(1))) void*)g,
        (__attribute__((address_space(3))) void*)l, 16, 0, 0);
}

// ---------------- kernel 1: fp32 -> bf16 concat ----------------
__global__ __launch_bounds__(256) void convert_kernel(const float* __restrict__ hi,
                                                      const float* __restrict__ hj,
                                                      u16* __restrict__ H) {
    int t = blockIdx.x * 256 + threadIdx.x;
    int e = t * 4;
    const int BD = BN_ * DD;
    const float* src = (e < BD) ? (hi + e) : (hj + (e - BD));
    float4 v = *(const float4*)src;
    U16x4 o;
    o.x = f2bf(v.x); o.y = f2bf(v.y); o.z = f2bf(v.z); o.w = f2bf(v.w);
    *(U16x4*)(H + e) = o;
}

// ---------------- kernel 2: Gram tile + row softmax partials ----------------
// Block tile 256 rows x 128 cols; 4 waves, wave w owns rows [w*64, w*64+64).
// Wave tile: 4x8 of 16x16x32 bf16 MFMA. LDS chunks XOR-swizzled: chunk
// (row, kc) lives at slot row*8 + (kc ^ (row&7)) -- swizzle applied to the
// SOURCE pointer so global_load_lds's lane-linear LDS dest is respected.
__global__ __launch_bounds__(256, 2) void gram_kernel(const u16* __restrict__ H,
                                                      float* __restrict__ Mpart,
                                                      float* __restrict__ Spart) {
    __shared__ u16 As[256 * 64];   // 32 KB
    __shared__ u16 Bs[128 * 64];   // 16 KB

    const int tid  = threadIdx.x;
    const int lane = tid & 63;
    const int wid  = tid >> 6;
    const int quad = lane >> 4;
    const int ln15 = lane & 15;
    const int rowBase = blockIdx.y * 256;
    const int colBase = blockIdx.x * 128;
    const int waveRow = wid * 64;

    floatx4 acc[4][8];
#pragma unroll
    for (int i = 0; i < 4; i++)
#pragma unroll
        for (int j = 0; j < 8; j++) acc[i][j] = (floatx4)0.0f;

    for (int k0 = 0; k0 < DD; k0 += 64) {
        // stage A: 256x64 = 2048 16B-chunks, 8 rounds of 256 threads
#pragma unroll
        for (int i = 0; i < 8; i++) {
            int c_lin = i * 256 + tid;          // LDS slot index
            int row   = c_lin >> 3;             // 0..255
            int kc    = (c_lin & 7) ^ (row & 7); // source chunk (swizzle inverse)
            async_copy16(H + (size_t)(rowBase + row) * DD + k0 + kc * 8,
                         &As[c_lin * 8]);
        }
        // stage B: 128x64 = 1024 chunks, 4 rounds
#pragma unroll
        for (int i = 0; i < 4; i++) {
            int c_lin = i * 256 + tid;
            int row   = c_lin >> 3;             // 0..127
            int kc    = (c_lin & 7) ^ (row & 7);
            async_copy16(H + (size_t)(colBase + row) * DD + k0 + kc * 8,
                         &Bs[c_lin * 8]);
        }
        __syncthreads();

#pragma unroll
        for (int kk = 0; kk < 2; kk++) {
            int ck = kk * 4 + quad;             // K-chunk index 0..7
            short8 a[4], b[8];
#pragma unroll
            for (int tm = 0; tm < 4; tm++) {
                int r = waveRow + tm * 16 + ln15;
                a[tm] = *(const short8*)&As[(r * 8 + (ck ^ (r & 7))) * 8];
            }
#pragma unroll
            for (int tn = 0; tn < 8; tn++) {
                int r = tn * 16 + ln15;
                b[tn] = *(const short8*)&Bs[(r * 8 + (ck ^ (r & 7))) * 8];
            }
#pragma unroll
            for (int tm = 0; tm < 4; tm++)
#pragma unroll
                for (int tn = 0; tn < 8; tn++)
                    acc[tm][tn] = __builtin_amdgcn_mfma_f32_16x16x32_bf16(
                        a[tm], b[tn], acc[tm][tn], 0, 0, 0);
        }
        __syncthreads();
    }

    // Epilogue: per-row max + sumexp over this wave's 128 cols.
    // C/D layout: col = ln15, row = quad*4 + reg (per 16x16 subtile).
    // Waves own disjoint rows -> no cross-wave merge.
#pragma unroll
    for (int tm = 0; tm < 4; tm++) {
#pragma unroll
        for (int r = 0; r < 4; r++) {
            int grow = rowBase + waveRow + tm * 16 + quad * 4 + r;
            float vals[8];
            float vmax = -FLT_MAX;
#pragma unroll
            for (int tn = 0; tn < 8; tn++) {
                float v = SCALE * acc[tm][tn][r];
                int gcol = colBase + tn * 16 + ln15;
                v = (gcol == grow) ? -FLT_MAX : v;
                vals[tn] = v;
                vmax = fmaxf(vmax, v);
            }
#pragma unroll
            for (int msk = 1; msk < 16; msk <<= 1)
                vmax = fmaxf(vmax, __shfl_xor(vmax, msk));
            float s = 0.0f;
#pragma unroll
            for (int tn = 0; tn < 8; tn++) s += __expf(vals[tn] - vmax);
#pragma unroll
            for (int msk = 1; msk < 16; msk <<= 1) s += __shfl_xor(s, msk);
            if (ln15 == 0) {
                size_t idx = (size_t)grow * 64 + blockIdx.x;  // row-major partials
                Mpart[idx] = vmax;
                Spart[idx] = s;
            }
        }
    }
}

// ---------------- kernel 3: sum of positive dots (exact fp32) ----------------
// sum_N pos = 4/temp' ... loss contribution = -(4/N) * sum_e hi[e]*hj[e]
__global__ __launch_bounds__(256) void pos_kernel(const float* __restrict__ hi,
                                                  const float* __restrict__ hj,
                                                  float* __restrict__ out) {
    __shared__ float red[4];
    const float4* a4 = (const float4*)hi;
    const float4* b4 = (const float4*)hj;
    int t = blockIdx.x * 256 + threadIdx.x;    // 65536 threads
    float dot = 0.0f;
#pragma unroll
    for (int i = 0; i < 8; i++) {              // 524288 float4 pairs total
        float4 a = a4[t + i * 65536];
        float4 b = b4[t + i * 65536];
        dot += a.x * b.x + a.y * b.y + a.z * b.z + a.w * b.w;
    }
#pragma unroll
    for (int msk = 1; msk < 64; msk <<= 1) dot += __shfl_xor(dot, msk);
    int lane = threadIdx.x & 63, wid = threadIdx.x >> 6;
    if (lane == 0) red[wid] = dot;
    __syncthreads();
    if (threadIdx.x == 0) {
        float s = red[0] + red[1] + red[2] + red[3];
        atomicAdd(out, s * (-4.0f / (float)NN));
    }
}

// ---------------- kernel 4: combine partials -> sum(lse)/N ----------------
// Row-major partials: row r's 64 (m,s) pairs are contiguous.
__global__ __launch_bounds__(256) void lse_kernel(const float* __restrict__ Mpart,
                                                  const float* __restrict__ Spart,
                                                  float* __restrict__ out) {
    __shared__ float red[256];
    int tid = threadIdx.x;
    int r = blockIdx.x * 256 + tid;            // 32 blocks x 256 rows
    const float4* M4 = (const float4*)(Mpart + (size_t)r * 64);
    const float4* S4 = (const float4*)(Spart + (size_t)r * 64);
    float m = -FLT_MAX;
    float4 mv[16];
#pragma unroll
    for (int i = 0; i < 16; i++) {
        float4 v = M4[i];
        mv[i] = v;
        m = fmaxf(m, fmaxf(fmaxf(v.x, v.y), fmaxf(v.z, v.w)));
    }
    float s = 0.0f;
#pragma unroll
    for (int i = 0; i < 16; i++) {
        float4 sv = S4[i];
        s += sv.x * __expf(mv[i].x - m) + sv.y * __expf(mv[i].y - m) +
             sv.z * __expf(mv[i].z - m) + sv.w * __expf(mv[i].w - m);
    }
    float lse = m + logf(s);
    red[tid] = lse;
    __syncthreads();
    for (int st = 128; st > 0; st >>= 1) {
        if (tid < st) red[tid] += red[tid + st];
        __syncthreads();
    }
    if (tid == 0) atomicAdd(out, red[0] * (1.0f / (float)NN));
}

extern "C" void kernel_launch(void* const* d_in, const int* in_sizes, int n_in,
                              void* d_out, int out_size, void* d_ws, size_t ws_size,
                              hipStream_t stream) {
    const float* hi = (const float*)d_in[0];
    const float* hj = (const float*)d_in[1];
    float* out = (float*)d_out;

    u16*   H     = (u16*)d_ws;                                            // 8 MB
    float* Mpart = (float*)((char*)d_ws + (size_t)8 * 1024 * 1024);       // 2 MB
    float* Spart = (float*)((char*)d_ws + (size_t)10 * 1024 * 1024);      // 2 MB

    hipMemsetAsync(d_out, 0, sizeof(float), stream);

    convert_kernel<<<4096, 256, 0, stream>>>(hi, hj, H);

    dim3 gg(64, 32);   // 64 col tiles x 32 row tiles
    gram_kernel<<<gg, 256, 0, stream>>>(H, Mpart, Spart);

    pos_kernel<<<256, 256, 0, stream>>>(hi, hj, out);

    lse_kernel<<<32, 256, 0, stream>>>(Mpart, Spart, out);
}

// Round 3
// 158.075 us; speedup vs baseline: 1.5648x; 1.0124x over previous
//
#include <hip/hip_runtime.h>
#include <hip/hip_bf16.h>
#include <float.h>

// B=4096, D=512, N=8192, temp=0.5
#define BN_ 4096
#define DD  512
#define NN  8192
#define SCALE 2.0f   // 1/temperature

typedef unsigned short u16;
typedef __attribute__((ext_vector_type(8))) short short8;   // 8 bf16 = 4 VGPRs
typedef __attribute__((ext_vector_type(4))) float floatx4;  // MFMA acc

struct alignas(8) U16x4 { u16 x, y, z, w; };

__device__ __forceinline__ u16 f2bf(float f) {
    union { float f; unsigned u; } c; c.f = f;
    unsigned u = c.u;
    unsigned r = (u + 0x7fffu + ((u >> 16) & 1u)) >> 16;   // RNE
    return (u16)r;
}

__device__ __forceinline__ void async_copy16(const u16* g, u16* l) {
    __builtin_amdgcn_global_load_lds(
        (const __attribute__((address_space(1))) void*)g,
        (__attribute__((address_space(3))) void*)l, 16, 0, 0);
}

// ------------- kernel 1: fp32 -> bf16 concat, fused positive-pair dot -------------
// Thread t handles flat elems [4t,4t+4) of BOTH hi and hj (same offset) so the
// positive dot products come for free with the conversion reads.
__global__ __launch_bounds__(256) void convert_pos_kernel(const float* __restrict__ hi,
                                                          const float* __restrict__ hj,
                                                          u16* __restrict__ H,
                                                          float* __restrict__ out) {
    __shared__ float red[4];
    int t = blockIdx.x * 256 + threadIdx.x;     // 2048 blocks -> 524288 threads
    int e = t * 4;
    const int BD = BN_ * DD;
    float4 a = *(const float4*)(hi + e);
    float4 b = *(const float4*)(hj + e);
    U16x4 oa, ob;
    oa.x = f2bf(a.x); oa.y = f2bf(a.y); oa.z = f2bf(a.z); oa.w = f2bf(a.w);
    ob.x = f2bf(b.x); ob.y = f2bf(b.y); ob.z = f2bf(b.z); ob.w = f2bf(b.w);
    *(U16x4*)(H + e) = oa;
    *(U16x4*)(H + BD + e) = ob;
    float dot = a.x * b.x + a.y * b.y + a.z * b.z + a.w * b.w;
#pragma unroll
    for (int msk = 1; msk < 64; msk <<= 1) dot += __shfl_xor(dot, msk);
    int lane = threadIdx.x & 63, wid = threadIdx.x >> 6;
    if (lane == 0) red[wid] = dot;
    __syncthreads();
    if (threadIdx.x == 0) {
        float s = red[0] + red[1] + red[2] + red[3];
        atomicAdd(out, s * (-4.0f / (float)NN));   // -(sum pos)/N
    }
}

// ------------- kernel 2: symmetric Gram, lower-triangle tiles only -------------
// Tile (bi,bj), bi>=bj, 128x128. 4 waves as 2x2 grid of 64x64 wave tiles
// (4x4 of 16x16x32 bf16 MFMA). Row-reduce gives partials for tile-row bi
// (slot bj); column-reduce of the SAME accumulators gives partials for
// tile-row bj (slot bi) -- the transpose tile for free. LDS chunk (row,kc)
// XOR-swizzled at slot row*8 + (kc ^ (row&7)) via the source pointer.
__global__ __launch_bounds__(256, 3) void gram_kernel(const u16* __restrict__ H,
                                                      float* __restrict__ Mpart,
                                                      float* __restrict__ Spart) {
    __shared__ u16 As[128 * 64];    // 16 KB
    __shared__ u16 Bs[128 * 64];    // 16 KB
    __shared__ float Rm[2][128], Rs[2][128];   // row partials per wc
    __shared__ float Cm[2][128], Cs[2][128];   // col partials per wr

    const int tid  = threadIdx.x;
    const int lane = tid & 63;
    const int wid  = tid >> 6;
    const int quad = lane >> 4;
    const int ln15 = lane & 15;
    const int wr = wid >> 1, wc = wid & 1;

    // lower-triangle decode: blockIdx.x in [0, 2080)
    int t = blockIdx.x;
    int bi = (int)((sqrtf(8.0f * (float)t + 1.0f) - 1.0f) * 0.5f);
    while ((bi + 1) * (bi + 2) / 2 <= t) bi++;
    while (bi * (bi + 1) / 2 > t) bi--;
    const int bj = t - bi * (bi + 1) / 2;
    const bool diag = (bi == bj);
    const int biBase = bi * 128, bjBase = bj * 128;

    // staging pointers, hoisted (B source = A source + uniform delta)
    const u16* srcA[4];
    int ldsOff[4];
#pragma unroll
    for (int j = 0; j < 4; j++) {
        int c   = j * 256 + tid;        // chunk 0..1023
        int row = c >> 3;               // 0..127
        int kc  = (c & 7) ^ (row & 7);  // swizzle inverse on source side
        srcA[j]   = H + (size_t)(biBase + row) * DD + kc * 8;
        ldsOff[j] = c * 8;
    }
    const ptrdiff_t dB = (ptrdiff_t)(bjBase - biBase) * DD;

    floatx4 acc[4][4];
#pragma unroll
    for (int i = 0; i < 4; i++)
#pragma unroll
        for (int j = 0; j < 4; j++) acc[i][j] = (floatx4)0.0f;

    for (int k0 = 0; k0 < DD; k0 += 64) {
#pragma unroll
        for (int j = 0; j < 4; j++) async_copy16(srcA[j] + k0,      &As[ldsOff[j]]);
#pragma unroll
        for (int j = 0; j < 4; j++) async_copy16(srcA[j] + dB + k0, &Bs[ldsOff[j]]);
        __syncthreads();

#pragma unroll
        for (int kk = 0; kk < 2; kk++) {
            int ck = kk * 4 + quad;     // K-chunk 0..7 within the 64-wide tile
            short8 a[4], b[4];
#pragma unroll
            for (int tm = 0; tm < 4; tm++) {
                int r = wr * 64 + tm * 16 + ln15;
                a[tm] = *(const short8*)&As[(r * 8 + (ck ^ (r & 7))) * 8];
            }
#pragma unroll
            for (int tn = 0; tn < 4; tn++) {
                int r = wc * 64 + tn * 16 + ln15;
                b[tn] = *(const short8*)&Bs[(r * 8 + (ck ^ (r & 7))) * 8];
            }
#pragma unroll
            for (int tm = 0; tm < 4; tm++)
#pragma unroll
                for (int tn = 0; tn < 4; tn++)
                    acc[tm][tn] = __builtin_amdgcn_mfma_f32_16x16x32_bf16(
                        a[tm], b[tn], acc[tm][tn], 0, 0, 0);
        }
        __syncthreads();
    }

    // scale in place; mask self-similarity on diagonal tiles
    // C/D layout: local row = tm*16 + quad*4 + reg, local col = tn*16 + ln15
#pragma unroll
    for (int tm = 0; tm < 4; tm++)
#pragma unroll
        for (int tn = 0; tn < 4; tn++)
#pragma unroll
            for (int r = 0; r < 4; r++) {
                float v = SCALE * acc[tm][tn][r];
                if (diag) {
                    int lrow = wr * 64 + tm * 16 + quad * 4 + r;
                    int lcol = wc * 64 + tn * 16 + ln15;
                    if (lrow == lcol) v = -FLT_MAX;
                }
                acc[tm][tn][r] = v;
            }

    // row pass: per-row max+sumexp over this wave's 64 cols
#pragma unroll
    for (int tm = 0; tm < 4; tm++) {
#pragma unroll
        for (int r = 0; r < 4; r++) {
            float vmax = -FLT_MAX;
#pragma unroll
            for (int tn = 0; tn < 4; tn++) vmax = fmaxf(vmax, acc[tm][tn][r]);
#pragma unroll
            for (int msk = 1; msk < 16; msk <<= 1)
                vmax = fmaxf(vmax, __shfl_xor(vmax, msk));
            float s = 0.0f;
#pragma unroll
            for (int tn = 0; tn < 4; tn++) s += __expf(acc[tm][tn][r] - vmax);
#pragma unroll
            for (int msk = 1; msk < 16; msk <<= 1) s += __shfl_xor(s, msk);
            if (ln15 == 0) {
                int x = wr * 64 + tm * 16 + quad * 4 + r;
                Rm[wc][x] = vmax; Rs[wc][x] = s;
            }
        }
    }

    // col pass (transpose tile): per-col max+sumexp over this wave's 64 rows
    if (!diag) {
#pragma unroll
        for (int tn = 0; tn < 4; tn++) {
            float cm = -FLT_MAX;
#pragma unroll
            for (int tm = 0; tm < 4; tm++)
#pragma unroll
                for (int r = 0; r < 4; r++) cm = fmaxf(cm, acc[tm][tn][r]);
            cm = fmaxf(cm, __shfl_xor(cm, 16));
            cm = fmaxf(cm, __shfl_xor(cm, 32));
            float s = 0.0f;
#pragma unroll
            for (int tm = 0; tm < 4; tm++)
#pragma unroll
                for (int r = 0; r < 4; r++) s += __expf(acc[tm][tn][r] - cm);
            s += __shfl_xor(s, 16);
            s += __shfl_xor(s, 32);
            if (quad == 0) {
                int y = wc * 64 + tn * 16 + ln15;
                Cm[wr][y] = cm; Cs[wr][y] = s;
            }
        }
    }
    __syncthreads();

    // merge wave halves, write slot-major partials: Mpart[slot*NN + globalRow]
    if (tid < 128) {
        float m0 = Rm[0][tid], m1 = Rm[1][tid];
        float s0 = Rs[0][tid], s1 = Rs[1][tid];
        float m = fmaxf(m0, m1);
        float s = s0 * __expf(m0 - m) + s1 * __expf(m1 - m);
        Mpart[(size_t)bj * NN + biBase + tid] = m;
        Spart[(size_t)bj * NN + biBase + tid] = s;
    } else if (!diag) {
        int y = tid - 128;
        float m0 = Cm[0][y], m1 = Cm[1][y];
        float s0 = Cs[0][y], s1 = Cs[1][y];
        float m = fmaxf(m0, m1);
        float s = s0 * __expf(m0 - m) + s1 * __expf(m1 - m);
        Mpart[(size_t)bi * NN + bjBase + y] = m;
        Spart[(size_t)bi * NN + bjBase + y] = s;
    }
}

// ------------- kernel 3: combine 64 slot-partials per row -> sum(lse)/N -------------
__global__ __launch_bounds__(256) void lse_kernel(const float* __restrict__ Mpart,
                                                  const float* __restrict__ Spart,
                                                  float* __restrict__ out) {
    __shared__ float red[256];
    int tid = threadIdx.x;
    int r = blockIdx.x * 256 + tid;            // 32 blocks x 256 rows
    float m = -FLT_MAX, s = 0.0f;
#pragma unroll 8
    for (int c = 0; c < 64; c++) {
        float mc = Mpart[(size_t)c * NN + r];  // coalesced: lane-stride 4B
        float sc = Spart[(size_t)c * NN + r];
        float mn = fmaxf(m, mc);
        s = s * __expf(m - mn) + sc * __expf(mc - mn);
        m = mn;
    }
    float lse = m + logf(s);
    red[tid] = lse;
    __syncthreads();
    for (int st = 128; st > 0; st >>= 1) {
        if (tid < st) red[tid] += red[tid + st];
        __syncthreads();
    }
    if (tid == 0) atomicAdd(out, red[0] * (1.0f / (float)NN));
}

extern "C" void kernel_launch(void* const* d_in, const int* in_sizes, int n_in,
                              void* d_out, int out_size, void* d_ws, size_t ws_size,
                              hipStream_t stream) {
    const float* hi = (const float*)d_in[0];
    const float* hj = (const float*)d_in[1];
    float* out = (float*)d_out;

    u16*   H     = (u16*)d_ws;                                            // 8 MB
    float* Mpart = (float*)((char*)d_ws + (size_t)8 * 1024 * 1024);       // 2 MB
    float* Spart = (float*)((char*)d_ws + (size_t)10 * 1024 * 1024);      // 2 MB

    hipMemsetAsync(d_out, 0, sizeof(float), stream);

    convert_pos_kernel<<<2048, 256, 0, stream>>>(hi, hj, H, out);

    gram_kernel<<<2080, 256, 0, stream>>>(H, Mpart, Spart);   // 65*64/2 tiles

    lse_kernel<<<32, 256, 0, stream>>>(Mpart, Spart, out);
}